// Round 2
// baseline (3124.878 us; speedup 1.0000x reference)
//
#include <hip/hip_runtime.h>
#include <math.h>

#define BB 2
#define LL 4096
#define DM 1024
#define DI 2048
#define NH 32
#define HD 64
#define NSTATE 64
#define CONVD 2176
#define RAWC 2208      // CONVD + NH (xBC columns + dt columns of in_proj output)
#define NC 16
#define CK 256

__device__ __forceinline__ float sigmoidf_(float x) { return 1.f / (1.f + expf(-x)); }
__device__ __forceinline__ float softplusf_(float x) { return (x > 20.f) ? x : log1pf(expf(x)); }

// Inclusive Hillis-Steele scan over 256 values in LDS. On return sc[] holds
// the inclusive cumsum (sc[255] = total).
__device__ __forceinline__ float block_scan256(float v, float* sc, int tid) {
    sc[tid] = v;
    __syncthreads();
    for (int off = 1; off < 256; off <<= 1) {
        float t = 0.f;
        if (tid >= off) t = sc[tid - off];
        __syncthreads();
        sc[tid] += t;
        __syncthreads();
    }
    return sc[tid];
}

// C[m,n] = sum_k A[m,k] * Bw[n,k]   (A: MxK row-major, Bw: NxK row-major)
__global__ __launch_bounds__(256) void gemm_nt(const float* __restrict__ A,
                                               const float* __restrict__ Bw,
                                               float* __restrict__ C,
                                               int M, int N, int K) {
    __shared__ float As[16][64 + 1];
    __shared__ float Bs[16][64 + 1];
    int tid = threadIdx.x;
    int tx = tid & 15, ty = tid >> 4;
    int n0 = blockIdx.x * 64, m0 = blockIdx.y * 64;
    float acc[4][4] = {};
    for (int k0 = 0; k0 < K; k0 += 16) {
        #pragma unroll
        for (int i = 0; i < 4; ++i) {
            int idx = tid + i * 256;
            int r = idx >> 4;      // 0..63
            int kk = idx & 15;     // 0..15
            As[kk][r] = A[(size_t)(m0 + r) * K + k0 + kk];
            float bv = 0.f;
            if (n0 + r < N) bv = Bw[(size_t)(n0 + r) * K + k0 + kk];
            Bs[kk][r] = bv;
        }
        __syncthreads();
        #pragma unroll
        for (int kk = 0; kk < 16; ++kk) {
            float av[4], bv[4];
            #pragma unroll
            for (int i = 0; i < 4; ++i) av[i] = As[kk][ty * 4 + i];
            #pragma unroll
            for (int j = 0; j < 4; ++j) bv[j] = Bs[kk][tx * 4 + j];
            #pragma unroll
            for (int i = 0; i < 4; ++i)
                #pragma unroll
                for (int j = 0; j < 4; ++j) acc[i][j] += av[i] * bv[j];
        }
        __syncthreads();
    }
    #pragma unroll
    for (int i = 0; i < 4; ++i)
        #pragma unroll
        for (int j = 0; j < 4; ++j) {
            int m = m0 + ty * 4 + i, n = n0 + tx * 4 + j;
            if (n < N) C[(size_t)m * N + n] = acc[i][j];
        }
}

// Depthwise conv7 along L (same padding) + bias + SiLU.
// Reads raw[b,l,ch] (ch in [0,CONVD)); writes xbc[b,l,ch].
__global__ __launch_bounds__(256) void conv_silu(const float* __restrict__ raw,
                                                 const float* __restrict__ cw,
                                                 const float* __restrict__ cb,
                                                 float* __restrict__ xbc) {
    int idx = blockIdx.x * 256 + threadIdx.x;
    if (idx >= BB * LL * CONVD) return;
    int ch = idx % CONVD;
    int l = (idx / CONVD) % LL;
    int b = idx / (CONVD * LL);
    float acc = cb[ch];
    #pragma unroll
    for (int j = 0; j < 7; ++j) {
        int lj = l + j - 3;
        if (lj >= 0 && lj < LL)
            acc += cw[ch * 7 + j] * raw[((size_t)b * LL + lj) * RAWC + ch];
    }
    xbc[((size_t)b * LL + l) * CONVD + ch] = acc * sigmoidf_(acc);
}

// dt[b,l,h] = softplus(raw[...,CONVD+h] + dt_bias[h])
__global__ __launch_bounds__(256) void dt_kernel(const float* __restrict__ raw,
                                                 const float* __restrict__ dt_bias,
                                                 float* __restrict__ dtb) {
    int idx = blockIdx.x * 256 + threadIdx.x;
    if (idx >= BB * LL * NH) return;
    int h = idx & 31;
    int row = idx >> 5;  // b*LL + l
    float x = raw[(size_t)row * RAWC + CONVD + h] + dt_bias[h];
    dtb[idx] = softplusf_(x);
}

// G[bc][l][s] = sum_n C[t(l),n] * B[t(s),n]  (only lower tiles st<=lt)
__global__ __launch_bounds__(256) void g_kernel(const float* __restrict__ xbc,
                                                float* __restrict__ G, int dir) {
    int lt = blockIdx.x, st = blockIdx.y, bc = blockIdx.z;
    if (st > lt) return;
    int b = bc / NC, c = bc % NC;
    __shared__ float Cs[64][65];
    __shared__ float Bs[64][65];
    int tid = threadIdx.x;
    int tx = tid & 15, ty = tid >> 4;
    #pragma unroll
    for (int i = 0; i < 16; ++i) {
        int e = tid + i * 256;
        int r = e >> 6, n = e & 63;
        int il = c * CK + lt * 64 + r;
        int is = c * CK + st * 64 + r;
        int tl = dir ? (LL - 1 - il) : il;
        int ts = dir ? (LL - 1 - is) : is;
        Cs[r][n] = xbc[((size_t)b * LL + tl) * CONVD + DI + NSTATE + n];
        Bs[r][n] = xbc[((size_t)b * LL + ts) * CONVD + DI + n];
    }
    __syncthreads();
    float acc[4][4] = {};
    #pragma unroll 8
    for (int n = 0; n < 64; ++n) {
        float cv[4], bv[4];
        #pragma unroll
        for (int i = 0; i < 4; ++i) cv[i] = Cs[ty * 4 + i][n];
        #pragma unroll
        for (int j = 0; j < 4; ++j) bv[j] = Bs[tx * 4 + j][n];
        #pragma unroll
        for (int i = 0; i < 4; ++i)
            #pragma unroll
            for (int j = 0; j < 4; ++j) acc[i][j] += cv[i] * bv[j];
    }
    #pragma unroll
    for (int i = 0; i < 4; ++i)
        #pragma unroll
        for (int j = 0; j < 4; ++j)
            G[((size_t)bc * CK + lt * 64 + ty * 4 + i) * CK + st * 64 + tx * 4 + j] = acc[i][j];
}

// states[b,c,h,p,n] = sum_l B[t(l),n] * exp(csum - Acum[l]) * dt[l] * x[t(l),h,p]
__global__ __launch_bounds__(256) void s1_states(const float* __restrict__ xbc,
                                                 const float* __restrict__ dtb,
                                                 const float* __restrict__ A_log,
                                                 float* __restrict__ states,
                                                 float* __restrict__ csum, int dir) {
    int h = blockIdx.x, c = blockIdx.y, b = blockIdx.z;
    int tid = threadIdx.x;
    __shared__ float sc[256];
    int l = tid;
    int gi = c * CK + l;
    int t = dir ? (LL - 1 - gi) : gi;
    float A = -expf(A_log[h]);
    float dtv = dtb[((size_t)b * LL + t) * NH + h];
    float acum = block_scan256(dtv * A, sc, tid);
    float cs = sc[255];
    if (tid == 0) csum[(b * NC + c) * NH + h] = cs;
    float w = expf(cs - acum) * dtv;
    __syncthreads();
    sc[l] = w;  // reuse sc to hold per-l weight
    __syncthreads();

    __shared__ float Xs[64][65];
    __shared__ float Bs[64][65];
    int tx = tid & 15, ty = tid >> 4;
    float acc[4][4] = {};
    for (int lt = 0; lt < 4; ++lt) {
        #pragma unroll
        for (int i = 0; i < 16; ++i) {
            int e = tid + i * 256;
            int r = e >> 6, q = e & 63;
            int ii = c * CK + lt * 64 + r;
            int tt = dir ? (LL - 1 - ii) : ii;
            size_t row = ((size_t)b * LL + tt) * CONVD;
            Xs[r][q] = xbc[row + h * 64 + q] * sc[lt * 64 + r];
            Bs[r][q] = xbc[row + DI + q];
        }
        __syncthreads();
        #pragma unroll 8
        for (int r = 0; r < 64; ++r) {
            float xv[4], bv[4];
            #pragma unroll
            for (int i = 0; i < 4; ++i) xv[i] = Xs[r][ty * 4 + i];
            #pragma unroll
            for (int j = 0; j < 4; ++j) bv[j] = Bs[r][tx * 4 + j];
            #pragma unroll
            for (int i = 0; i < 4; ++i)
                #pragma unroll
                for (int j = 0; j < 4; ++j) acc[i][j] += xv[i] * bv[j];
        }
        __syncthreads();
    }
    size_t base = (((size_t)(b * NC + c) * NH + h)) * (64 * 64);
    #pragma unroll
    for (int i = 0; i < 4; ++i)
        #pragma unroll
        for (int j = 0; j < 4; ++j)
            states[base + (ty * 4 + i) * 64 + tx * 4 + j] = acc[i][j];
}

// In-place chunk-scan: states[z] <- prev[z], where
// prev[0]=0 ; prev[z] = prev[z-1]*exp(csum[z-1]) + states_old[z-1]
__global__ __launch_bounds__(256) void s2_scan(float* __restrict__ states,
                                               const float* __restrict__ csum) {
    int h = blockIdx.x, b = blockIdx.y, eo = blockIdx.z;
    int e = eo * 256 + threadIdx.x;  // 0..4095
    float run = 0.f;
    for (int z = 0; z < NC; ++z) {
        size_t base = (((size_t)(b * NC + z) * NH + h)) * (64 * 64);
        float s = states[base + e];       // read BEFORE overwrite (in-place)
        states[base + e] = run;
        float g = expf(csum[(b * NC + z) * NH + h]);
        run = run * g + s;
    }
}

// y[t(l),h,p] (=/+=) E[l] * ( sum_{s<=l} G[l,s]*Einv[s]*Xdt[s,p] + sum_n C[l,n]*prev[p,n] )
__global__ __launch_bounds__(256) void s3_out(const float* __restrict__ xbc,
                                              const float* __restrict__ dtb,
                                              const float* __restrict__ A_log,
                                              const float* __restrict__ G,
                                              const float* __restrict__ prev,
                                              float* __restrict__ y, int dir, int beta) {
    int lq = blockIdx.x, h = blockIdx.y, bc = blockIdx.z;
    int b = bc / NC, c = bc % NC;
    int tid = threadIdx.x;
    int tx = tid & 15, ty = tid >> 4;
    __shared__ float sAc[256];
    __shared__ float sEin[256];
    int l = tid;
    int gi = c * CK + l;
    int t = dir ? (LL - 1 - gi) : gi;
    float A = -expf(A_log[h]);
    float dtv = dtb[((size_t)b * LL + t) * NH + h];
    float acum = block_scan256(dtv * A, sAc, tid);
    sEin[l] = expf(-acum) * dtv;  // folded dt for Xdt staging
    __syncthreads();

    __shared__ float Gs[64][65];   // also reused as Cs
    __shared__ float Xs[64][65];   // also reused as Pv
    float acc[4][4] = {};
    for (int st = 0; st <= lq; ++st) {
        #pragma unroll
        for (int i = 0; i < 16; ++i) {
            int e = tid + i * 256;
            int r = e >> 6, q = e & 63;
            Gs[r][q] = G[((size_t)bc * CK + lq * 64 + r) * CK + st * 64 + q];
            int is = c * CK + st * 64 + r;
            int ts = dir ? (LL - 1 - is) : is;
            Xs[r][q] = xbc[((size_t)b * LL + ts) * CONVD + h * 64 + q] * sEin[st * 64 + r];
        }
        __syncthreads();
        if (st < lq) {
            #pragma unroll 4
            for (int ss = 0; ss < 64; ++ss) {
                float gv[4], xv[4];
                #pragma unroll
                for (int i = 0; i < 4; ++i) gv[i] = Gs[ty * 4 + i][ss];
                #pragma unroll
                for (int j = 0; j < 4; ++j) xv[j] = Xs[ss][tx * 4 + j];
                #pragma unroll
                for (int i = 0; i < 4; ++i)
                    #pragma unroll
                    for (int j = 0; j < 4; ++j) acc[i][j] += gv[i] * xv[j];
            }
        } else {
            // diagonal tile: include s<=l for dir0, s<l for dir1 (absorbs -diag)
            #pragma unroll 4
            for (int ss = 0; ss < 64; ++ss) {
                float gv[4], xv[4];
                #pragma unroll
                for (int i = 0; i < 4; ++i) gv[i] = Gs[ty * 4 + i][ss];
                #pragma unroll
                for (int j = 0; j < 4; ++j) xv[j] = Xs[ss][tx * 4 + j];
                #pragma unroll
                for (int i = 0; i < 4; ++i) {
                    int ll = ty * 4 + i;
                    float m = (ss + dir <= ll) ? 1.f : 0.f;
                    #pragma unroll
                    for (int j = 0; j < 4; ++j) acc[i][j] += m * gv[i] * xv[j];
                }
            }
        }
        __syncthreads();
    }

    // Y_off: reuse Gs as Cs[ll][n], Xs as Pv[p][n]
    {
        size_t pbase = (((size_t)(b * NC + c) * NH + h)) * (64 * 64);
        #pragma unroll
        for (int i = 0; i < 16; ++i) {
            int e = tid + i * 256;
            int r = e >> 6, q = e & 63;
            int il = c * CK + lq * 64 + r;
            int tl = dir ? (LL - 1 - il) : il;
            Gs[r][q] = xbc[((size_t)b * LL + tl) * CONVD + DI + NSTATE + q];  // C[l,n]
            Xs[r][q] = prev[pbase + r * 64 + q];                              // Pv[p][n]
        }
        __syncthreads();
        #pragma unroll 8
        for (int n = 0; n < 64; ++n) {
            float cv[4], pv[4];
            #pragma unroll
            for (int i = 0; i < 4; ++i) cv[i] = Gs[ty * 4 + i][n];
            #pragma unroll
            for (int j = 0; j < 4; ++j) pv[j] = Xs[tx * 4 + j][n];
            #pragma unroll
            for (int i = 0; i < 4; ++i)
                #pragma unroll
                for (int j = 0; j < 4; ++j) acc[i][j] += cv[i] * pv[j];
        }
    }

    #pragma unroll
    for (int i = 0; i < 4; ++i) {
        int ll = lq * 64 + ty * 4 + i;
        float El = expf(sAc[ll]);
        int il = c * CK + ll;
        int tl = dir ? (LL - 1 - il) : il;
        size_t yb = ((size_t)b * LL + tl) * DI + h * 64;
        #pragma unroll
        for (int j = 0; j < 4; ++j) {
            float v = El * acc[i][j];
            if (beta) y[yb + tx * 4 + j] += v;
            else      y[yb + tx * 4 + j]  = v;
        }
    }
}

// RMSNorm over DI + silu(z) gating, in place on y. z from its own buffer (stride DI).
__global__ __launch_bounds__(256) void norm_gate(const float* __restrict__ zbuf,
                                                 const float* __restrict__ norm_w,
                                                 float* __restrict__ y) {
    int row = blockIdx.x;  // b*LL + l
    int tid = threadIdx.x;
    float ss = 0.f;
    size_t yb = (size_t)row * DI;
    for (int i = tid; i < DI; i += 256) {
        float v = y[yb + i];
        ss += v * v;
    }
    #pragma unroll
    for (int off = 32; off > 0; off >>= 1) ss += __shfl_down(ss, off, 64);
    __shared__ float red[4];
    if ((tid & 63) == 0) red[tid >> 6] = ss;
    __syncthreads();
    float tot = red[0] + red[1] + red[2] + red[3];
    float rstd = rsqrtf(tot / DI + 1e-5f);
    for (int i = tid; i < DI; i += 256) {
        float z = zbuf[yb + i];
        float g = z * sigmoidf_(z);
        y[yb + i] = y[yb + i] * rstd * norm_w[i] * g;
    }
}

extern "C" void kernel_launch(void* const* d_in, const int* in_sizes, int n_in,
                              void* d_out, int out_size, void* d_ws, size_t ws_size,
                              hipStream_t stream) {
    const float* u          = (const float*)d_in[0];
    const float* in_proj_w  = (const float*)d_in[1];
    const float* conv_w     = (const float*)d_in[2];
    const float* conv_b     = (const float*)d_in[3];
    const float* dt_bias    = (const float*)d_in[4];
    const float* A_log      = (const float*)d_in[5];
    const float* norm_w     = (const float*)d_in[6];
    const float* out_proj_w = (const float*)d_in[7];
    float* out = (float*)d_out;

    // Workspace layout (floats): total 52,690,944 = 210.8 MB
    float* ws  = (float*)d_ws;
    float* z   = ws;                               // B*L*DI   = 16,777,216
    float* raw = z + (size_t)BB * LL * DI;         // B*L*RAWC = 18,087,936
    float* xbc = raw + (size_t)BB * LL * RAWC;     // B*L*CONVD= 17,825,792
    float* y   = raw;  // alias: raw is dead after conv_silu + dt_kernel

    // Scratch inside d_out (free until final GEMM overwrites): 6,554,624 floats = 26.2 MB <= 33.5 MB
    float* states = (float*)d_out;                              // 4,194,304
    float* G      = states + (size_t)BB * NC * NH * 64 * 64;    // 2,097,152
    float* dtb    = G + (size_t)BB * NC * CK * CK;              // 262,144
    float* csum   = dtb + (size_t)BB * LL * NH;                 // 1,024
    float* prev   = states;  // s2_scan transforms states -> prev in place

    dim3 blk(256);
    int M = BB * LL;  // 8192

    // 1) in_proj GEMM, split into z part and xBC+dt part
    gemm_nt<<<dim3(DI / 64, M / 64), blk, 0, stream>>>(u, in_proj_w, z, M, DI, DM);
    gemm_nt<<<dim3((RAWC + 63) / 64, M / 64), blk, 0, stream>>>(
        u, in_proj_w + (size_t)DI * DM, raw, M, RAWC, DM);
    // 2) depthwise conv + silu
    conv_silu<<<(BB * LL * CONVD + 255) / 256, blk, 0, stream>>>(raw, conv_w, conv_b, xbc);
    // 3) dt softplus
    dt_kernel<<<(BB * LL * NH + 255) / 256, blk, 0, stream>>>(raw, dt_bias, dtb);
    // 4) bidirectional SSD (dir0 stores y, dir1 accumulates)
    for (int dir = 0; dir < 2; ++dir) {
        g_kernel<<<dim3(4, 4, BB * NC), blk, 0, stream>>>(xbc, G, dir);
        s1_states<<<dim3(NH, NC, BB), blk, 0, stream>>>(xbc, dtb, A_log, states, csum, dir);
        s2_scan<<<dim3(NH, BB, 16), blk, 0, stream>>>(states, csum);
        s3_out<<<dim3(4, NH, BB * NC), blk, 0, stream>>>(xbc, dtb, A_log, G, prev, y, dir, dir);
    }
    // 5) RMSNorm + gate
    norm_gate<<<M, blk, 0, stream>>>(z, norm_w, y);
    // 6) out_proj GEMM -> d_out (overwrites the scratch region)
    gemm_nt<<<dim3(DM / 64, M / 64), blk, 0, stream>>>(y, out_proj_w, out, M, DM, DI);
}

// Round 3
// 1431.387 us; speedup vs baseline: 2.1831x; 2.1831x over previous
//
#include <hip/hip_runtime.h>
#include <math.h>

#define BB 2
#define LL 4096
#define DM 1024
#define DI 2048
#define NH 32
#define HD 64
#define NSTATE 64
#define CONVD 2176
#define RAWC 2208      // CONVD + NH
#define NC 16
#define CK 256

typedef __attribute__((ext_vector_type(8))) short bf16x8;
typedef __attribute__((ext_vector_type(4))) float f32x4;

__device__ __forceinline__ float sigmoidf_(float x) { return 1.f / (1.f + expf(-x)); }
__device__ __forceinline__ float softplusf_(float x) { return (x > 20.f) ? x : log1pf(expf(x)); }

__device__ __forceinline__ unsigned short f2bf(float v) {
    unsigned u = __float_as_uint(v);
    unsigned r = (u + 0x7FFFu + ((u >> 16) & 1u)) >> 16;
    return (unsigned short)r;
}
__device__ __forceinline__ float bf2f(unsigned short h) {
    return __uint_as_float(((unsigned)h) << 16);
}

typedef const __attribute__((address_space(1))) void gvoid_t;
typedef __attribute__((address_space(3))) void lvoid_t;
__device__ __forceinline__ void gload_lds16(const void* g, void* l) {
    __builtin_amdgcn_global_load_lds((gvoid_t*)g, (lvoid_t*)l, 16, 0, 0);
}

// ---------------- pack kernels (fp32 -> bf16 hi/lo) ----------------

// X (M x K f32) -> Y (M x 2K bf16): [hi | lo]
__global__ __launch_bounds__(256) void pack_hilo(const float* __restrict__ X,
                                                 unsigned short* __restrict__ Y,
                                                 int M, int K) {
    int idx = blockIdx.x * 256 + threadIdx.x;
    if (idx >= M * K) return;
    int m = idx / K, k = idx % K;
    float v = X[(size_t)m * K + k];
    unsigned short hi = f2bf(v);
    unsigned short lo = f2bf(v - bf2f(hi));
    size_t base = (size_t)m * (2 * K);
    Y[base + k] = hi;
    Y[base + K + k] = lo;
}

// W (N x K f32, N true rows) -> Y (Npad x 3K bf16): [hi | lo | hi], zero-padded rows
__global__ __launch_bounds__(256) void pack_w3(const float* __restrict__ W,
                                               unsigned short* __restrict__ Y,
                                               int N, int Npad, int K) {
    int idx = blockIdx.x * 256 + threadIdx.x;
    if (idx >= Npad * K) return;
    int n = idx / K, k = idx % K;
    float v = (n < N) ? W[(size_t)n * K + k] : 0.f;
    unsigned short hi = f2bf(v);
    unsigned short lo = f2bf(v - bf2f(hi));
    size_t base = (size_t)n * (3 * K);
    Y[base + k] = hi;
    Y[base + K + k] = lo;
    Y[base + 2 * K + k] = hi;
}

// ---------------- MFMA GEMM: C[m,n] = sum_k A[m,k]*B[n,k] (bf16x3) ----------------
// A: [hi|lo] packed, row stride Astride=2K, k' in [0,3K) remapped phys=(k'<K?k':k'-K)
// B3: Npad x 3K bf16 [hi|lo|hi]. C: M x N fp32 (row stride N).
__global__ __launch_bounds__(256) void gemm_mfma(const unsigned short* __restrict__ A,
                                                 const unsigned short* __restrict__ B3,
                                                 float* __restrict__ C,
                                                 int M, int N, int K, int Astride, int Kp) {
    __shared__ short As[128 * 32];
    __shared__ short Bs[128 * 32];
    int tid = threadIdx.x;
    int lane = tid & 63;
    int w = tid >> 6;
    int wr = w >> 1, wc = w & 1;
    int n0 = blockIdx.x * 128, m0 = blockIdx.y * 128;
    f32x4 acc[4][4] = {};

    for (int k0 = 0; k0 < Kp; k0 += 32) {
        int ka = (k0 < K) ? k0 : k0 - K;  // A phys k ([hi|hi|lo] -> [hi|lo] storage)
        #pragma unroll
        for (int p = 0; p < 2; ++p) {
            int s = p * 256 + tid;        // segment 0..511 (16B each)
            int row = s >> 2;
            int sub = (s & 3) ^ ((row >> 1) & 3);  // inverse-swizzled global source
            gload_lds16(A + (size_t)(m0 + row) * Astride + ka + sub * 8, &As[s * 8]);
            gload_lds16(B3 + (size_t)(n0 + row) * Kp + k0 + sub * 8, &Bs[s * 8]);
        }
        __syncthreads();
        bf16x8 af[4], bfv[4];
        #pragma unroll
        for (int i = 0; i < 4; ++i) {
            int rowA = wr * 64 + i * 16 + (lane & 15);
            int slotA = (lane >> 4) ^ ((rowA >> 1) & 3);  // swizzled read
            af[i] = *(const bf16x8*)&As[rowA * 32 + slotA * 8];
            int rowB = wc * 64 + i * 16 + (lane & 15);
            int slotB = (lane >> 4) ^ ((rowB >> 1) & 3);
            bfv[i] = *(const bf16x8*)&Bs[rowB * 32 + slotB * 8];
        }
        #pragma unroll
        for (int i = 0; i < 4; ++i)
            #pragma unroll
            for (int j = 0; j < 4; ++j)
                acc[i][j] = __builtin_amdgcn_mfma_f32_16x16x32_bf16(af[i], bfv[j], acc[i][j], 0, 0, 0);
        __syncthreads();
    }

    #pragma unroll
    for (int i = 0; i < 4; ++i) {
        int mbase = m0 + wr * 64 + i * 16 + (lane >> 4) * 4;
        #pragma unroll
        for (int j = 0; j < 4; ++j) {
            int n = n0 + wc * 64 + j * 16 + (lane & 15);
            if (n < N) {
                #pragma unroll
                for (int r = 0; r < 4; ++r)
                    C[(size_t)(mbase + r) * N + n] = acc[i][j][r];
            }
        }
    }
}

// ---------------- conv / dt ----------------

__global__ __launch_bounds__(256) void conv_silu(const float* __restrict__ raw,
                                                 const float* __restrict__ cw,
                                                 const float* __restrict__ cb,
                                                 float* __restrict__ xbc) {
    int idx = blockIdx.x * 256 + threadIdx.x;
    if (idx >= BB * LL * CONVD) return;
    int ch = idx % CONVD;
    int l = (idx / CONVD) % LL;
    int b = idx / (CONVD * LL);
    float acc = cb[ch];
    #pragma unroll
    for (int j = 0; j < 7; ++j) {
        int lj = l + j - 3;
        if (lj >= 0 && lj < LL)
            acc += cw[ch * 7 + j] * raw[((size_t)b * LL + lj) * RAWC + ch];
    }
    xbc[((size_t)b * LL + l) * CONVD + ch] = acc * sigmoidf_(acc);
}

__global__ __launch_bounds__(256) void dt_kernel(const float* __restrict__ raw,
                                                 const float* __restrict__ dt_bias,
                                                 float* __restrict__ dtb) {
    int idx = blockIdx.x * 256 + threadIdx.x;
    if (idx >= BB * LL * NH) return;
    int h = idx & 31;
    int row = idx >> 5;
    float x = raw[(size_t)row * RAWC + CONVD + h] + dt_bias[h];
    dtb[idx] = softplusf_(x);
}

// ---------------- SSD ----------------

__device__ __forceinline__ float block_scan256(float v, float* sc, int tid) {
    sc[tid] = v;
    __syncthreads();
    for (int off = 1; off < 256; off <<= 1) {
        float t = 0.f;
        if (tid >= off) t = sc[tid - off];
        __syncthreads();
        sc[tid] += t;
        __syncthreads();
    }
    return sc[tid];
}

__global__ __launch_bounds__(256) void g_kernel(const float* __restrict__ xbc,
                                                float* __restrict__ G, int dir) {
    int lt = blockIdx.x, st = blockIdx.y, bc = blockIdx.z;
    if (st > lt) return;
    int b = bc / NC, c = bc % NC;
    __shared__ float Cs[64][65];
    __shared__ float Bs[64][65];
    int tid = threadIdx.x;
    int tx = tid & 15, ty = tid >> 4;
    #pragma unroll
    for (int i = 0; i < 16; ++i) {
        int e = tid + i * 256;
        int r = e >> 6, n = e & 63;
        int il = c * CK + lt * 64 + r;
        int is = c * CK + st * 64 + r;
        int tl = dir ? (LL - 1 - il) : il;
        int ts = dir ? (LL - 1 - is) : is;
        Cs[r][n] = xbc[((size_t)b * LL + tl) * CONVD + DI + NSTATE + n];
        Bs[r][n] = xbc[((size_t)b * LL + ts) * CONVD + DI + n];
    }
    __syncthreads();
    float acc[4][4] = {};
    #pragma unroll 8
    for (int n = 0; n < 64; ++n) {
        float cv[4], bv[4];
        #pragma unroll
        for (int i = 0; i < 4; ++i) cv[i] = Cs[ty * 4 + i][n];
        #pragma unroll
        for (int j = 0; j < 4; ++j) bv[j] = Bs[tx * 4 + j][n];
        #pragma unroll
        for (int i = 0; i < 4; ++i)
            #pragma unroll
            for (int j = 0; j < 4; ++j) acc[i][j] += cv[i] * bv[j];
    }
    #pragma unroll
    for (int i = 0; i < 4; ++i)
        #pragma unroll
        for (int j = 0; j < 4; ++j)
            G[((size_t)bc * CK + lt * 64 + ty * 4 + i) * CK + st * 64 + tx * 4 + j] = acc[i][j];
}

__global__ __launch_bounds__(256) void s1_states(const float* __restrict__ xbc,
                                                 const float* __restrict__ dtb,
                                                 const float* __restrict__ A_log,
                                                 float* __restrict__ states,
                                                 float* __restrict__ csum, int dir) {
    int h = blockIdx.x, c = blockIdx.y, b = blockIdx.z;
    int tid = threadIdx.x;
    __shared__ float sc[256];
    int l = tid;
    int gi = c * CK + l;
    int t = dir ? (LL - 1 - gi) : gi;
    float A = -expf(A_log[h]);
    float dtv = dtb[((size_t)b * LL + t) * NH + h];
    float acum = block_scan256(dtv * A, sc, tid);
    float cs = sc[255];
    if (tid == 0) csum[(b * NC + c) * NH + h] = cs;
    float wgt = expf(cs - acum) * dtv;
    __syncthreads();
    sc[l] = wgt;
    __syncthreads();

    __shared__ float Xs[64][65];
    __shared__ float Bs[64][65];
    int tx = tid & 15, ty = tid >> 4;
    float acc[4][4] = {};
    for (int lt = 0; lt < 4; ++lt) {
        #pragma unroll
        for (int i = 0; i < 16; ++i) {
            int e = tid + i * 256;
            int r = e >> 6, q = e & 63;
            int ii = c * CK + lt * 64 + r;
            int tt = dir ? (LL - 1 - ii) : ii;
            size_t row = ((size_t)b * LL + tt) * CONVD;
            Xs[r][q] = xbc[row + h * 64 + q] * sc[lt * 64 + r];
            Bs[r][q] = xbc[row + DI + q];
        }
        __syncthreads();
        #pragma unroll 8
        for (int r = 0; r < 64; ++r) {
            float xv[4], bv[4];
            #pragma unroll
            for (int i = 0; i < 4; ++i) xv[i] = Xs[r][ty * 4 + i];
            #pragma unroll
            for (int j = 0; j < 4; ++j) bv[j] = Bs[r][tx * 4 + j];
            #pragma unroll
            for (int i = 0; i < 4; ++i)
                #pragma unroll
                for (int j = 0; j < 4; ++j) acc[i][j] += xv[i] * bv[j];
        }
        __syncthreads();
    }
    size_t base = (((size_t)(b * NC + c) * NH + h)) * (64 * 64);
    #pragma unroll
    for (int i = 0; i < 4; ++i)
        #pragma unroll
        for (int j = 0; j < 4; ++j)
            states[base + (ty * 4 + i) * 64 + tx * 4 + j] = acc[i][j];
}

__global__ __launch_bounds__(256) void s2_scan(float* __restrict__ states,
                                               const float* __restrict__ csum) {
    int h = blockIdx.x, b = blockIdx.y, eo = blockIdx.z;
    int e = eo * 256 + threadIdx.x;
    float run = 0.f;
    for (int z = 0; z < NC; ++z) {
        size_t base = (((size_t)(b * NC + z) * NH + h)) * (64 * 64);
        float s = states[base + e];
        states[base + e] = run;
        float g = expf(csum[(b * NC + z) * NH + h]);
        run = run * g + s;
    }
}

__global__ __launch_bounds__(256) void s3_out(const float* __restrict__ xbc,
                                              const float* __restrict__ dtb,
                                              const float* __restrict__ A_log,
                                              const float* __restrict__ G,
                                              const float* __restrict__ prev,
                                              float* __restrict__ y, int dir, int beta) {
    int lq = blockIdx.x, h = blockIdx.y, bc = blockIdx.z;
    int b = bc / NC, c = bc % NC;
    int tid = threadIdx.x;
    int tx = tid & 15, ty = tid >> 4;
    __shared__ float sAc[256];
    __shared__ float sEin[256];
    int l = tid;
    int gi = c * CK + l;
    int t = dir ? (LL - 1 - gi) : gi;
    float A = -expf(A_log[h]);
    float dtv = dtb[((size_t)b * LL + t) * NH + h];
    float acum = block_scan256(dtv * A, sAc, tid);
    sEin[l] = expf(-acum) * dtv;
    __syncthreads();

    __shared__ float Gs[64][65];
    __shared__ float Xs[64][65];
    float acc[4][4] = {};
    for (int st = 0; st <= lq; ++st) {
        #pragma unroll
        for (int i = 0; i < 16; ++i) {
            int e = tid + i * 256;
            int r = e >> 6, q = e & 63;
            Gs[r][q] = G[((size_t)bc * CK + lq * 64 + r) * CK + st * 64 + q];
            int is = c * CK + st * 64 + r;
            int ts = dir ? (LL - 1 - is) : is;
            Xs[r][q] = xbc[((size_t)b * LL + ts) * CONVD + h * 64 + q] * sEin[st * 64 + r];
        }
        __syncthreads();
        if (st < lq) {
            #pragma unroll 4
            for (int ss = 0; ss < 64; ++ss) {
                float gv[4], xv[4];
                #pragma unroll
                for (int i = 0; i < 4; ++i) gv[i] = Gs[ty * 4 + i][ss];
                #pragma unroll
                for (int j = 0; j < 4; ++j) xv[j] = Xs[ss][tx * 4 + j];
                #pragma unroll
                for (int i = 0; i < 4; ++i)
                    #pragma unroll
                    for (int j = 0; j < 4; ++j) acc[i][j] += gv[i] * xv[j];
            }
        } else {
            #pragma unroll 4
            for (int ss = 0; ss < 64; ++ss) {
                float gv[4], xv[4];
                #pragma unroll
                for (int i = 0; i < 4; ++i) gv[i] = Gs[ty * 4 + i][ss];
                #pragma unroll
                for (int j = 0; j < 4; ++j) xv[j] = Xs[ss][tx * 4 + j];
                #pragma unroll
                for (int i = 0; i < 4; ++i) {
                    int ll = ty * 4 + i;
                    float m = (ss + dir <= ll) ? 1.f : 0.f;
                    #pragma unroll
                    for (int j = 0; j < 4; ++j) acc[i][j] += m * gv[i] * xv[j];
                }
            }
        }
        __syncthreads();
    }

    {
        size_t pbase = (((size_t)(b * NC + c) * NH + h)) * (64 * 64);
        #pragma unroll
        for (int i = 0; i < 16; ++i) {
            int e = tid + i * 256;
            int r = e >> 6, q = e & 63;
            int il = c * CK + lq * 64 + r;
            int tl = dir ? (LL - 1 - il) : il;
            Gs[r][q] = xbc[((size_t)b * LL + tl) * CONVD + DI + NSTATE + q];
            Xs[r][q] = prev[pbase + r * 64 + q];
        }
        __syncthreads();
        #pragma unroll 8
        for (int n = 0; n < 64; ++n) {
            float cv[4], pv[4];
            #pragma unroll
            for (int i = 0; i < 4; ++i) cv[i] = Gs[ty * 4 + i][n];
            #pragma unroll
            for (int j = 0; j < 4; ++j) pv[j] = Xs[tx * 4 + j][n];
            #pragma unroll
            for (int i = 0; i < 4; ++i)
                #pragma unroll
                for (int j = 0; j < 4; ++j) acc[i][j] += cv[i] * pv[j];
        }
    }

    #pragma unroll
    for (int i = 0; i < 4; ++i) {
        int ll = lq * 64 + ty * 4 + i;
        float El = expf(sAc[ll]);
        int il = c * CK + ll;
        int tl = dir ? (LL - 1 - il) : il;
        size_t yb = ((size_t)b * LL + tl) * DI + h * 64;
        #pragma unroll
        for (int j = 0; j < 4; ++j) {
            float v = El * acc[i][j];
            if (beta) y[yb + tx * 4 + j] += v;
            else      y[yb + tx * 4 + j]  = v;
        }
    }
}

__global__ __launch_bounds__(256) void norm_gate(const float* __restrict__ zbuf,
                                                 const float* __restrict__ norm_w,
                                                 float* __restrict__ y) {
    int row = blockIdx.x;
    int tid = threadIdx.x;
    float ss = 0.f;
    size_t yb = (size_t)row * DI;
    for (int i = tid; i < DI; i += 256) {
        float v = y[yb + i];
        ss += v * v;
    }
    #pragma unroll
    for (int off = 32; off > 0; off >>= 1) ss += __shfl_down(ss, off, 64);
    __shared__ float red[4];
    if ((tid & 63) == 0) red[tid >> 6] = ss;
    __syncthreads();
    float tot = red[0] + red[1] + red[2] + red[3];
    float rstd = rsqrtf(tot / DI + 1e-5f);
    for (int i = tid; i < DI; i += 256) {
        float z = zbuf[yb + i];
        float g = z * sigmoidf_(z);
        y[yb + i] = y[yb + i] * rstd * norm_w[i] * g;
    }
}

extern "C" void kernel_launch(void* const* d_in, const int* in_sizes, int n_in,
                              void* d_out, int out_size, void* d_ws, size_t ws_size,
                              hipStream_t stream) {
    const float* u          = (const float*)d_in[0];
    const float* in_proj_w  = (const float*)d_in[1];
    const float* conv_w     = (const float*)d_in[2];
    const float* conv_b     = (const float*)d_in[3];
    const float* dt_bias    = (const float*)d_in[4];
    const float* A_log      = (const float*)d_in[5];
    const float* norm_w     = (const float*)d_in[6];
    const float* out_proj_w = (const float*)d_in[7];
    float* out = (float*)d_out;

    // ws layout (floats), 211 MB total (same footprint as the passing round-2):
    float* ws  = (float*)d_ws;
    float* z   = ws;                               // 16,777,216 f (67.1 MB)
    float* raw = z + (size_t)BB * LL * DI;         // 18,087,936 f (72.4 MB)
    float* xbc = raw + (size_t)BB * LL * RAWC;     // 17,825,792 f (71.3 MB)
    float* y   = raw;                              // alias: raw dead after conv+dt

    // bf16 pack buffers, aliased into dead regions:
    unsigned short* u2     = (unsigned short*)d_out;   // 8192x2048 bf16 = 33.5 MB (d_out exactly)
    unsigned short* w2z    = (unsigned short*)xbc;     // 2048x3072 bf16 = 12.6 MB (xbc not yet live)
    unsigned short* w2raw  = w2z + (size_t)2048 * 3072;// 2304x3072 bf16 = 14.2 MB
    unsigned short* y2     = (unsigned short*)z;       // 8192x4096 bf16 = 67.1 MB (z dead post-norm)
    unsigned short* wout2  = (unsigned short*)xbc;     // 1024x6144 bf16 = 12.6 MB (xbc dead post-SSD)

    // SSD scratch inside d_out (u2 dead by then; overwritten by final GEMM at the end):
    float* states = (float*)d_out;                              // 4,194,304 f
    float* G      = states + (size_t)BB * NC * NH * 64 * 64;    // 2,097,152 f
    float* dtb    = G + (size_t)BB * NC * CK * CK;              //   262,144 f
    float* csum   = dtb + (size_t)BB * LL * NH;                 //     1,024 f
    float* prev   = states;

    dim3 blk(256);
    int M = BB * LL;  // 8192

    // 0) packs for in_proj
    pack_hilo<<<(M * DM + 255) / 256, blk, 0, stream>>>(u, u2, M, DM);
    pack_w3<<<(2048 * DM + 255) / 256, blk, 0, stream>>>(in_proj_w, w2z, 2048, 2048, DM);
    pack_w3<<<(2304 * DM + 255) / 256, blk, 0, stream>>>(in_proj_w + (size_t)DI * DM, w2raw, RAWC, 2304, DM);
    // 1) in_proj GEMMs (bf16x3): z (N=2048), raw (N=2208, padded 2304)
    gemm_mfma<<<dim3(2048 / 128, M / 128), blk, 0, stream>>>(u2, w2z, z, M, 2048, DM, 2 * DM, 3 * DM);
    gemm_mfma<<<dim3(2304 / 128, M / 128), blk, 0, stream>>>(u2, w2raw, raw, M, RAWC, DM, 2 * DM, 3 * DM);
    // 2) conv + silu ; 3) dt
    conv_silu<<<(BB * LL * CONVD + 255) / 256, blk, 0, stream>>>(raw, conv_w, conv_b, xbc);
    dt_kernel<<<(BB * LL * NH + 255) / 256, blk, 0, stream>>>(raw, dt_bias, dtb);
    // 4) bidirectional SSD (dir0 stores y, dir1 accumulates)
    for (int dir = 0; dir < 2; ++dir) {
        g_kernel<<<dim3(4, 4, BB * NC), blk, 0, stream>>>(xbc, G, dir);
        s1_states<<<dim3(NH, NC, BB), blk, 0, stream>>>(xbc, dtb, A_log, states, csum, dir);
        s2_scan<<<dim3(NH, BB, 16), blk, 0, stream>>>(states, csum);
        s3_out<<<dim3(4, NH, BB * NC), blk, 0, stream>>>(xbc, dtb, A_log, G, prev, y, dir, dir);
    }
    // 5) RMSNorm + gate
    norm_gate<<<M, blk, 0, stream>>>(z, norm_w, y);
    // 6) out_proj (bf16x3): pack y and weights, then GEMM -> d_out
    pack_hilo<<<(M * DI + 255) / 256, blk, 0, stream>>>(y, y2, M, DI);
    pack_w3<<<(1024 * DI + 255) / 256, blk, 0, stream>>>(out_proj_w, wout2, DM, DM, DI);
    gemm_mfma<<<dim3(1024 / 128, M / 128), blk, 0, stream>>>(y2, wout2, out, M, DM, DI, 2 * DI, 3 * DI);
}